// Round 9
// baseline (421.639 us; speedup 1.0000x reference)
//
#include <hip/hip_runtime.h>
#include <hip/hip_bf16.h>
#include <math.h>

#define B_   16
#define L_   2048
#define DIN  512
#define HID_ 512
#define H_   8
#define D_   64
#define U_   40
#define BH   (B_*H_)     // 128

typedef unsigned short u16;
typedef unsigned int u32;
typedef unsigned long long u64;
typedef __bf16 bf16x8 __attribute__((ext_vector_type(8)));
typedef float f32x4 __attribute__((ext_vector_type(4)));

__device__ __forceinline__ u16 f2bf(float x) {            // RNE via HW cvt
  __bf16 b = (__bf16)x;
  return __builtin_bit_cast(unsigned short, b);
}
__device__ __forceinline__ float bf2f(u16 h) {
  return __uint_as_float(((unsigned)h) << 16);
}
__device__ __forceinline__ float bflo(u32 x) { return __uint_as_float(x << 16); }
__device__ __forceinline__ float bfhi(u32 x) { return __uint_as_float(x & 0xFFFF0000u); }
__device__ __forceinline__ u32 pk2(float a, float b) {
  return (u32)f2bf(a) | ((u32)f2bf(b) << 16);
}
__device__ __forceinline__ void gload16(const u16* g, u16* l) {
  __builtin_amdgcn_global_load_lds(
      (__attribute__((address_space(1))) void*)(g),
      (__attribute__((address_space(3))) void*)(l), 16, 0, 0);
}
__device__ __forceinline__ u64 mkkey(float Mv, int l) {
  u32 fb = __float_as_uint(Mv);
  u32 mapped = (fb & 0x80000000u) ? ~fb : (fb | 0x80000000u);
  return ((u64)mapped << 32) | (u64)(0xFFFFFFFFu - (u32)l);
}

// ---------------- weight split+transpose (all 3): W f32 -> Bt3[y] bf16 [512][1024] ---
__global__ __launch_bounds__(256)
void wsplit3_kernel(const float* __restrict__ Wq, const float* __restrict__ Wk,
                    const float* __restrict__ Wv, u16* __restrict__ Bt3) {
  const float* W = (blockIdx.y == 0) ? Wq : (blockIdx.y == 1) ? Wk : Wv;
  u16* Bt = Bt3 + (size_t)blockIdx.y * 524288;
  int tid = blockIdx.x * 256 + threadIdx.x;
  int n = tid & 511, k = tid >> 9;
  float a = W[(size_t)k * 512 + n];
  u16 hi = f2bf(a);
  u16 lo = f2bf(a - bf2f(hi));
  int kb = k >> 5, kc = k & 31;
  int slotH = kc >> 3, wi = kc & 7;
  int swzH = (slotH     ^ (n & 7)) << 3;
  int swzL = ((4+slotH) ^ (n & 7)) << 3;
  Bt[(size_t)n * 1024 + kb * 64 + swzH + wi] = hi;
  Bt[(size_t)n * 1024 + kb * 64 + swzL + wi] = lo;
}

// ---------------- projection GEMM, 2-phase pipelined --------------------------------
// A: global->registers (no LDS). B: double-buffered global_load_lds.
// One barrier per kb; next-kb loads issued before current MFMA.
// NPASS=3: 3-term split (q/k, f32 out). NPASS=1: plain bf16 (v), OUTBF -> u16 out.
template<int NPASS, int OUTBF>
__global__ __launch_bounds__(256, 3)
void gemm_proj(const float* __restrict__ A0, const float* __restrict__ A1,
               const u16* __restrict__ Bt0, const u16* __restrict__ Bt1,
               void* __restrict__ C0, void* __restrict__ C1) {
  __shared__ u16 Bs[2 * 128 * 64];
  const float* A = blockIdx.z ? A1 : A0;
  const u16* Bt  = blockIdx.z ? Bt1 : Bt0;
  void* C        = blockIdx.z ? C1 : C0;
  const int t = threadIdx.x;
  const int w = t >> 6, lane = t & 63;
  const int lhi = lane >> 4, l16 = lane & 15;
  const int row0 = blockIdx.x * 128, col0 = blockIdx.y * 128;
  const int wrow = (w >> 1) * 64, wcol = (w & 1) * 64;

  const u16* gB = Bt + (size_t)(col0 + w * 32 + (lane >> 3)) * 1024 + (lane & 7) * 8;
  const float* Abase = A + (size_t)(row0 + wrow + l16) * 512 + lhi * 8;

  f32x4 acc[4][4];
  #pragma unroll
  for (int i = 0; i < 4; ++i)
    #pragma unroll
    for (int j = 0; j < 4; ++j) acc[i][j] = (f32x4){0.f, 0.f, 0.f, 0.f};

  float4 ra[8], rb[8];
  bf16x8 aH[4], aL[4];

#define STAGEB(KB, NB)                                                          \
  { u16* lB = &Bs[(NB) * 8192 + (w * 32) * 64];                                 \
    _Pragma("unroll") for (int i = 0; i < 4; ++i)                               \
      gload16(gB + (KB) * 64 + (size_t)i * 8 * 1024, lB + i * 8 * 64); }

#define LOADA(DST, KB)                                                          \
  { _Pragma("unroll") for (int i = 0; i < 4; ++i) {                             \
      const float4* pa = reinterpret_cast<const float4*>(                       \
          Abase + (size_t)i * 16 * 512 + (KB) * 32);                            \
      DST[2*i] = pa[0]; DST[2*i+1] = pa[1]; } }

#define CVTA(SRC)                                                               \
  { _Pragma("unroll") for (int i = 0; i < 4; ++i) {                             \
      float4 x = SRC[2*i], y = SRC[2*i+1];                                      \
      aH[i][0]=(__bf16)x.x; aH[i][1]=(__bf16)x.y; aH[i][2]=(__bf16)x.z;         \
      aH[i][3]=(__bf16)x.w; aH[i][4]=(__bf16)y.x; aH[i][5]=(__bf16)y.y;         \
      aH[i][6]=(__bf16)y.z; aH[i][7]=(__bf16)y.w;                               \
      if constexpr (NPASS == 3) {                                               \
        aL[i][0]=(__bf16)(x.x-(float)aH[i][0]); aL[i][1]=(__bf16)(x.y-(float)aH[i][1]); \
        aL[i][2]=(__bf16)(x.z-(float)aH[i][2]); aL[i][3]=(__bf16)(x.w-(float)aH[i][3]); \
        aL[i][4]=(__bf16)(y.x-(float)aH[i][4]); aL[i][5]=(__bf16)(y.y-(float)aH[i][5]); \
        aL[i][6]=(__bf16)(y.z-(float)aH[i][6]); aL[i][7]=(__bf16)(y.w-(float)aH[i][7]); } } }

#define MFMAP(NB)                                                               \
  { bf16x8 bH[4];                                                               \
    _Pragma("unroll") for (int j = 0; j < 4; ++j) {                             \
      int cb = wcol + j * 16 + l16;                                             \
      bH[j] = *reinterpret_cast<const bf16x8*>(                                 \
          &Bs[(NB) * 8192 + cb * 64 + ((lhi ^ (cb & 7)) << 3)]); }              \
    _Pragma("unroll") for (int i = 0; i < 4; ++i)                               \
      _Pragma("unroll") for (int j = 0; j < 4; ++j)                             \
        acc[i][j] = __builtin_amdgcn_mfma_f32_16x16x32_bf16(aH[i], bH[j], acc[i][j], 0, 0, 0); \
    if constexpr (NPASS == 3) {                                                 \
      _Pragma("unroll") for (int j = 0; j < 4; ++j) {                           \
        int cb = wcol + j * 16 + l16;                                           \
        bf16x8 bL = *reinterpret_cast<const bf16x8*>(                           \
            &Bs[(NB) * 8192 + cb * 64 + (((4 + lhi) ^ (cb & 7)) << 3)]);        \
        _Pragma("unroll") for (int i = 0; i < 4; ++i)                           \
          acc[i][j] = __builtin_amdgcn_mfma_f32_16x16x32_bf16(aH[i], bL, acc[i][j], 0, 0, 0); } \
      _Pragma("unroll") for (int i = 0; i < 4; ++i)                             \
        _Pragma("unroll") for (int j = 0; j < 4; ++j)                           \
          acc[i][j] = __builtin_amdgcn_mfma_f32_16x16x32_bf16(aL[i], bH[j], acc[i][j], 0, 0, 0); } }

#define STEP(KB, CUR, NXT)                                                      \
  { if ((KB) < 15) { STAGEB((KB)+1, ((KB)+1)&1); LOADA(NXT, (KB)+1); }          \
    CVTA(CUR);                                                                  \
    MFMAP((KB)&1);                                                              \
    __syncthreads(); }

  STAGEB(0, 0)
  LOADA(ra, 0)
  __syncthreads();

  STEP(0, ra, rb)  STEP(1, rb, ra)  STEP(2, ra, rb)  STEP(3, rb, ra)
  STEP(4, ra, rb)  STEP(5, rb, ra)  STEP(6, ra, rb)  STEP(7, rb, ra)
  STEP(8, ra, rb)  STEP(9, rb, ra)  STEP(10, ra, rb) STEP(11, rb, ra)
  STEP(12, ra, rb) STEP(13, rb, ra) STEP(14, ra, rb) STEP(15, rb, ra)

#undef STEP
#undef MFMAP
#undef CVTA
#undef LOADA
#undef STAGEB

  #pragma unroll
  for (int i = 0; i < 4; ++i)
    #pragma unroll
    for (int j = 0; j < 4; ++j)
      #pragma unroll
      for (int r = 0; r < 4; ++r) {
        size_t idx = (size_t)(row0 + wrow + i * 16 + lhi * 4 + r) * 512
                     + col0 + wcol + j * 16 + l16;
        if constexpr (OUTBF) ((u16*)C)[idx] = f2bf(acc[i][j][r]);
        else                 ((float*)C)[idx] = acc[i][j][r];
      }
}

// ---------------- dot + per-chunk top-40 candidates (exact f32) ---------------------
__global__ __launch_bounds__(256)
void dotsel_kernel(const float* __restrict__ qp, const float* __restrict__ kp,
                   const int* __restrict__ indx, u64* __restrict__ cand) {
  __shared__ u64 keys[256];
  __shared__ u64 wmax[2][4];
  const int bh = blockIdx.x, ch = blockIdx.y;
  const int t = threadIdx.x, w = t >> 6, lane = t & 63;
  const size_t boff = (size_t)bh * 131072;
  const int l0 = ch * 256 + w * 64;
  const float cUL = 40.0f / 2048.0f;
  const int li = lane >> 4;
  const int dq = lane & 15;

  #pragma unroll 4
  for (int i = 0; i < 16; ++i) {
    int l = l0 + i * 4 + li;
    int ls = indx[l];
    float4 q4 = *reinterpret_cast<const float4*>(&qp[boff + (size_t)l * 64 + dq * 4]);
    float4 k4 = *reinterpret_cast<const float4*>(&kp[boff + (size_t)ls * 64 + dq * 4]);
    float p = q4.x * k4.x + q4.y * k4.y + q4.z * k4.z + q4.w * k4.w;
    p += __shfl_xor(p, 1, 64);
    p += __shfl_xor(p, 2, 64);
    p += __shfl_xor(p, 4, 64);
    p += __shfl_xor(p, 8, 64);
    if (dq == 0) {
      float Mv = p - p * cUL;
      keys[w * 64 + i * 4 + li] = mkkey(Mv, l);
    }
  }
  __syncthreads();

  u64 myk = keys[t];
  for (int u = 0; u < U_; ++u) {
    u64 b = myk;
    #pragma unroll
    for (int off = 32; off >= 1; off >>= 1) {
      u64 v = __shfl_xor(b, off, 64);
      if (v > b) b = v;
    }
    if (lane == 0) wmax[u & 1][w] = b;
    __syncthreads();
    const u64* wm = wmax[u & 1];
    u64 m = wm[0];
    if (wm[1] > m) m = wm[1];
    if (wm[2] > m) m = wm[2];
    if (wm[3] > m) m = wm[3];
    if (myk == m) myk = 0;              // unique keys: owner clears
    if (t == 0) cand[((size_t)(bh * 8 + ch)) * U_ + u] = m;
  }
}

// ---------------- merge 8x40 candidates -> global top-40 (1 wave per bh) ------------
__global__ __launch_bounds__(64)
void merge_topk(const u64* __restrict__ cand, int* __restrict__ mtop) {
  const int bh = blockIdx.x;
  const int lane = threadIdx.x;
  u64 c0 = cand[(size_t)bh * 320 + 0 * 64 + lane];
  u64 c1 = cand[(size_t)bh * 320 + 1 * 64 + lane];
  u64 c2 = cand[(size_t)bh * 320 + 2 * 64 + lane];
  u64 c3 = cand[(size_t)bh * 320 + 3 * 64 + lane];
  u64 c4 = cand[(size_t)bh * 320 + 4 * 64 + lane];
  for (int u = 0; u < U_; ++u) {
    u64 b = c0;
    if (c1 > b) b = c1;
    if (c2 > b) b = c2;
    if (c3 > b) b = c3;
    if (c4 > b) b = c4;
    #pragma unroll
    for (int off = 32; off >= 1; off >>= 1) {
      u64 v = __shfl_xor(b, off, 64);
      if (v > b) b = v;
    }
    if (c0 == b) c0 = 0;
    if (c1 == b) c1 = 0;
    if (c2 == b) c2 = 0;
    if (c3 == b) c3 = 0;
    if (c4 == b) c4 = 0;
    if (lane == 0) mtop[bh * U_ + u] = (int)(0xFFFFFFFFu - (u32)b);
  }
}

// ---------------- gather selected q rows -> bf16, x0.125, 48-row padded -------------
__global__ __launch_bounds__(256)
void gather_q_kernel(const float* __restrict__ qp, const int* __restrict__ mtop,
                     u16* __restrict__ qredbf) {
  int tid = blockIdx.x * 256 + threadIdx.x;   // BH*48*64 total
  int s = tid >> 6;
  int d = tid & 63;
  int bh = s / 48;
  int u = s - bh * 48;
  float val = 0.f;
  if (u < U_) {
    int m = mtop[bh * U_ + u];
    val = qp[(size_t)bh * (L_ * D_) + (size_t)m * D_ + d] * 0.125f;
  }
  qredbf[tid] = f2bf(val);
}

// ---------------- scores via MFMA: stages K from f32 kp; S bf16, mask fused ---------
__global__ __launch_bounds__(256)
void scores_mfma(const u16* __restrict__ qredbf, const float* __restrict__ kp,
                 const int* __restrict__ mtop, u16* __restrict__ S) {
  __shared__ u16 As[48 * 64];
  __shared__ u16 Bs[128 * 64];
  __shared__ int ms[U_];
  const int bh = blockIdx.x;
  const int l0 = blockIdx.y * 128;
  const int t = threadIdx.x, w = t >> 6, lane = t & 63;
  const int lhi = lane >> 4, l16 = lane & 15;

  for (int e = t; e < 384; e += 256) {
    int r = e >> 3, s = e & 7;
    *reinterpret_cast<uint4*>(&As[r * 64 + ((s ^ (r & 7)) << 3)]) =
        *reinterpret_cast<const uint4*>(&qredbf[(size_t)bh * 3072 + e * 8]);
  }
  #pragma unroll
  for (int ee = 0; ee < 4; ++ee) {
    int e = t + ee * 256;
    int r = e >> 3, s = e & 7;
    const float* src = &kp[(size_t)bh * 131072 + (size_t)(l0 + r) * 64 + s * 8];
    float4 va = *reinterpret_cast<const float4*>(src);
    float4 vb = *reinterpret_cast<const float4*>(src + 4);
    uint4 w4 = make_uint4(pk2(va.x, va.y), pk2(va.z, va.w),
                          pk2(vb.x, vb.y), pk2(vb.z, vb.w));
    *reinterpret_cast<uint4*>(&Bs[r * 64 + ((s ^ (r & 7)) << 3)]) = w4;
  }
  if (t < U_) ms[t] = mtop[bh * U_ + t];
  __syncthreads();

  f32x4 acc[3][2];
  #pragma unroll
  for (int m = 0; m < 3; ++m)
    #pragma unroll
    for (int n = 0; n < 2; ++n) acc[m][n] = (f32x4){0.f, 0.f, 0.f, 0.f};

  #pragma unroll
  for (int ks = 0; ks < 2; ++ks) {
    bf16x8 a[3], b[2];
    #pragma unroll
    for (int m = 0; m < 3; ++m) {
      int r = m * 16 + l16;
      a[m] = *reinterpret_cast<const bf16x8*>(
          &As[r * 64 + (((ks * 4 + lhi) ^ (r & 7)) << 3)]);
    }
    #pragma unroll
    for (int n = 0; n < 2; ++n) {
      int cb = w * 32 + n * 16 + l16;
      b[n] = *reinterpret_cast<const bf16x8*>(
          &Bs[cb * 64 + (((ks * 4 + lhi) ^ (cb & 7)) << 3)]);
    }
    #pragma unroll
    for (int m = 0; m < 3; ++m)
      #pragma unroll
      for (int n = 0; n < 2; ++n)
        acc[m][n] = __builtin_amdgcn_mfma_f32_16x16x32_bf16(a[m], b[n], acc[m][n], 0, 0, 0);
  }

  #pragma unroll
  for (int m = 0; m < 3; ++m)
    #pragma unroll
    for (int n = 0; n < 2; ++n)
      #pragma unroll
      for (int r = 0; r < 4; ++r) {
        int u = m * 16 + lhi * 4 + r;
        if (u < U_) {
          int l = l0 + w * 32 + n * 16 + l16;
          float val = acc[m][n][r];
          if (l > ms[u]) val = -INFINITY;
          S[((size_t)bh * 48 + u) * 2048 + l] = f2bf(val);
        }
      }
}

// ---------------- row softmax over l, bf16 in-place (S -> P) ------------------------
__global__ __launch_bounds__(256)
void softmax_kernel(u16* __restrict__ S) {
  __shared__ float red[4];
  const int rr = blockIdx.x;            // bh*40 + u
  const int bh = rr / U_;
  const int u = rr - bh * U_;
  const int t = threadIdx.x;
  uint4* rp = reinterpret_cast<uint4*>(&S[((size_t)bh * 48 + u) * 2048]);
  uint4 raw = rp[t];
  float f[8];
  f[0] = bflo(raw.x); f[1] = bfhi(raw.x); f[2] = bflo(raw.y); f[3] = bfhi(raw.y);
  f[4] = bflo(raw.z); f[5] = bfhi(raw.z); f[6] = bflo(raw.w); f[7] = bfhi(raw.w);
  float m = f[0];
  #pragma unroll
  for (int i = 1; i < 8; ++i) m = fmaxf(m, f[i]);
  #pragma unroll
  for (int off = 32; off >= 1; off >>= 1) m = fmaxf(m, __shfl_xor(m, off, 64));
  if ((t & 63) == 0) red[t >> 6] = m;
  __syncthreads();
  m = fmaxf(fmaxf(red[0], red[1]), fmaxf(red[2], red[3]));
  __syncthreads();
  float s = 0.f;
  #pragma unroll
  for (int i = 0; i < 8; ++i) { f[i] = expf(f[i] - m); s += f[i]; }
  #pragma unroll
  for (int off = 32; off >= 1; off >>= 1) s += __shfl_xor(s, off, 64);
  if ((t & 63) == 0) red[t >> 6] = s;
  __syncthreads();
  s = red[0] + red[1] + red[2] + red[3];
  float inv = 1.0f / s;
  uint4 o;
  o.x = pk2(f[0] * inv, f[1] * inv);
  o.y = pk2(f[2] * inv, f[3] * inv);
  o.z = pk2(f[4] * inv, f[5] * inv);
  o.w = pk2(f[6] * inv, f[7] * inv);
  rp[t] = o;
}

// ---------------- PV via MFMA, split-K=8, V (bf16) transposed in-kernel -------------
__global__ __launch_bounds__(256)
void pv_mfma(const u16* __restrict__ Pbf, const u16* __restrict__ vbf,
             float* __restrict__ partial) {
  __shared__ u16 Ps[48 * 128];
  __shared__ u16 Vs[64 * 128];
  const int bh = blockIdx.x, kh = blockIdx.y;
  const int t = threadIdx.x, w = t >> 6, lane = t & 63;
  const int lhi = lane >> 4, l16 = lane & 15;
  const size_t vbase = (size_t)bh * 131072;
  f32x4 acc[3];
  #pragma unroll
  for (int m = 0; m < 3; ++m) acc[m] = (f32x4){0.f, 0.f, 0.f, 0.f};

  for (int ch = 0; ch < 2; ++ch) {
    const int lb = kh * 256 + ch * 128;
    for (int e = t; e < 768; e += 256) {
      int r = e >> 4, s = e & 15;
      int sw = (s & 8) | ((s & 7) ^ (r & 7));
      *reinterpret_cast<uint4*>(&Ps[r * 128 + (sw << 3)]) =
          *reinterpret_cast<const uint4*>(&Pbf[((size_t)bh * 48 + r) * 2048 + lb + s * 8]);
    }
    #pragma unroll
    for (int j = 0; j < 16; ++j) {
      int ll = w * 32 + 2 * j;
      u16 ua = vbf[vbase + (size_t)(lb + ll) * 64 + lane];
      u16 ub = vbf[vbase + (size_t)(lb + ll + 1) * 64 + lane];
      u32 pk = (u32)ua | ((u32)ub << 16);
      int s = ll >> 3;
      int sw = (s & 8) | ((s & 7) ^ (lane & 7));
      *reinterpret_cast<u32*>(&Vs[lane * 128 + (sw << 3) + (ll & 7)]) = pk;
    }
    __syncthreads();
    #pragma unroll
    for (int ks = 0; ks < 4; ++ks) {
      bf16x8 b;
      { int cb = w * 16 + l16; int s = ks * 4 + lhi;
        int sw = (s & 8) | ((s & 7) ^ (cb & 7));
        b = *reinterpret_cast<const bf16x8*>(&Vs[cb * 128 + (sw << 3)]); }
      #pragma unroll
      for (int m = 0; m < 3; ++m) {
        int r = m * 16 + l16; int s = ks * 4 + lhi;
        int sw = (s & 8) | ((s & 7) ^ (r & 7));
        bf16x8 a = *reinterpret_cast<const bf16x8*>(&Ps[r * 128 + (sw << 3)]);
        acc[m] = __builtin_amdgcn_mfma_f32_16x16x32_bf16(a, b, acc[m], 0, 0, 0);
      }
    }
    __syncthreads();
  }
  #pragma unroll
  for (int m = 0; m < 3; ++m)
    #pragma unroll
    for (int r = 0; r < 4; ++r) {
      int u = m * 16 + lhi * 4 + r;
      partial[(((size_t)kh * 128 + bh) * 48 + u) * 64 + w * 16 + l16] = acc[m][r];
    }
}

// ---------------- cumsum 2-phase over bf16 v -> f32 ctx -----------------------------
__global__ __launch_bounds__(256)
void cumsumA(const u16* __restrict__ vbf, float* __restrict__ seg32) {
  int bh = blockIdx.x, sg = blockIdx.y;
  int t = threadIdx.x, w = t >> 6, lane = t & 63;
  int g = sg * 4 + w;
  size_t base = (size_t)bh * 131072 + (size_t)g * 32 * 64;
  float s = 0.f;
  for (int i = 0; i < 32; ++i) s += bf2f(vbf[base + i * 64 + lane]);
  seg32[((size_t)bh * 64 + g) * 64 + lane] = s;
}
__global__ __launch_bounds__(256)
void cumsumB(const u16* __restrict__ vbf, const float* __restrict__ seg32,
             float* __restrict__ ctx) {
  int bh = blockIdx.x, sg = blockIdx.y;
  int t = threadIdx.x, w = t >> 6, lane = t & 63;
  int g = sg * 4 + w;
  float run = 0.f;
  for (int s = 0; s < g; ++s) run += seg32[((size_t)bh * 64 + s) * 64 + lane];
  size_t base = (size_t)bh * 131072 + (size_t)g * 32 * 64;
  for (int i = 0; i < 32; ++i) {
    run += bf2f(vbf[base + i * 64 + lane]);
    ctx[base + i * 64 + lane] = run;
  }
}

// ---------------- merge 8 partials + scatter into ctx -------------------------------
__global__ __launch_bounds__(256)
void scatter_kernel(const float* __restrict__ partial, const int* __restrict__ mtop,
                    float* __restrict__ ctx) {
  int tid = blockIdx.x * 256 + threadIdx.x;
  int s = tid >> 6;
  if (s >= BH * U_) return;
  int d = tid & 63;
  int bh = s / U_;
  int u = s - bh * U_;
  float a = 0.f;
  #pragma unroll
  for (int c = 0; c < 8; ++c)
    a += partial[(((size_t)(c * 128 + bh)) * 48 + u) * 64 + d];
  ctx[(size_t)bh * 131072 + (size_t)mtop[s] * 64 + d] = a;
}

// ---------------- Wo -> bf16, transposed + swizzled: WoT[j][512] --------------------
__global__ __launch_bounds__(256)
void wo_prep(const float* __restrict__ Wo, u16* __restrict__ WoT) {
  int tid = blockIdx.x * 256 + threadIdx.x;   // 32768
  int j = tid >> 9, k = tid & 511;
  float v = Wo[(size_t)k * 64 + j];
  int k0 = k & ~63, ko = k & 63;
  int ks = ko >> 5, kc = ko & 31;
  int slot = (ks * 4 + (kc >> 3)) ^ (j & 7);
  WoT[(size_t)j * 512 + k0 + (slot << 3) + (kc & 7)] = f2bf(v);
}

// ---------------- out GEMM via MFMA (plain bf16): out[M][64] = ctx @ Wo -------------
__global__ __launch_bounds__(256, 6)
void gemm_out(const float* __restrict__ ctx, const u16* __restrict__ WoT,
              float* __restrict__ out) {
  __shared__ u16 As[64 * 64];
  __shared__ u16 Bs[64 * 64];
  const int t = threadIdx.x, w = t >> 6, lane = t & 63;
  const int lhi = lane >> 4, l16 = lane & 15;
  const int row0 = blockIdx.x * 64;
  f32x4 acc[4];
  #pragma unroll
  for (int j = 0; j < 4; ++j) acc[j] = (f32x4){0.f, 0.f, 0.f, 0.f};

  for (int k0 = 0; k0 < 512; k0 += 64) {
    #pragma unroll
    for (int ii = 0; ii < 2; ++ii) {
      int e = t + ii * 256;
      int j = e >> 3, s = e & 7;
      gload16(WoT + (size_t)j * 512 + k0 + s * 8, Bs + (size_t)(w * 64 + ii * 256) * 8);
    }
    #pragma unroll
    for (int ii = 0; ii < 2; ++ii) {
      int e = t + ii * 256;
      int r = e >> 3, s = e & 7;
      const float* src = &ctx[(size_t)(row0 + r) * 512 + k0 + s * 8];
      float4 va = *reinterpret_cast<const float4*>(src);
      float4 vb = *reinterpret_cast<const float4*>(src + 4);
      uint4 w4 = make_uint4(pk2(va.x, va.y), pk2(va.z, va.w),
                            pk2(vb.x, vb.y), pk2(vb.z, vb.w));
      *reinterpret_cast<uint4*>(&As[r * 64 + ((s ^ (r & 7)) << 3)]) = w4;
    }
    __syncthreads();
    #pragma unroll
    for (int ks = 0; ks < 2; ++ks) {
      int r = w * 16 + l16;
      bf16x8 a = *reinterpret_cast<const bf16x8*>(
          &As[r * 64 + (((ks * 4 + lhi) ^ (r & 7)) << 3)]);
      #pragma unroll
      for (int jf = 0; jf < 4; ++jf) {
        int cb = jf * 16 + l16;
        bf16x8 b = *reinterpret_cast<const bf16x8*>(
            &Bs[cb * 64 + (((ks * 4 + lhi) ^ (cb & 7)) << 3)]);
        acc[jf] = __builtin_amdgcn_mfma_f32_16x16x32_bf16(a, b, acc[jf], 0, 0, 0);
      }
    }
    __syncthreads();
  }
  #pragma unroll
  for (int jf = 0; jf < 4; ++jf)
    #pragma unroll
    for (int r = 0; r < 4; ++r)
      out[(size_t)(row0 + w * 16 + lhi * 4 + r) * 64 + jf * 16 + l16] = acc[jf][r];
}

extern "C" void kernel_launch(void* const* d_in, const int* in_sizes, int n_in,
                              void* d_out, int out_size, void* d_ws, size_t ws_size,
                              hipStream_t stream) {
  const float* q_in = (const float*)d_in[0];
  const float* k_in = (const float*)d_in[1];
  const float* v_in = (const float*)d_in[2];
  const float* Wq   = (const float*)d_in[3];
  const float* Wk   = (const float*)d_in[4];
  const float* Wv   = (const float*)d_in[5];
  const float* Wo   = (const float*)d_in[6];
  const int*   indx = (const int*)d_in[7];
  float* out = (float*)d_out;

  float* ws = (float*)d_ws;
  float* qp   = ws;                         // 16,777,216 f (64 MiB)
  float* kp   = ws + 16777216;
  u16*   vbf  = (u16*)(ws + 33554432);      // 16M u16 (32 MiB) — v projection in bf16
  u64*   cand = (u64*)(ws + 50331648);      // 320 KiB
  u16*   WoT  = (u16*)cand;                 // 64 KiB — after cand dead
  u16*   qredbf = (u16*)(ws + 50593792);    // 393,216 u16
  int*   mtop = (int*)(ws + 50921472);      // 5,120 ints
  // d_out used as scratch for split weights (3 MiB of 8 MiB); gemm_out fully
  // overwrites d_out at the end, so this is replay-safe.
  u16*   Bt3  = (u16*)d_out;
  // qp region reuse (qp f32 dead after gather_q):
  u16*   S    = (u16*)qp;                   // 12.6M u16 (24 MiB)
  float* ctx  = qp;                         // cumsum output (after S dead)
  // kp region reuse (kp f32 dead after scores_mfma):
  float* partial = kp;                      // 3,145,728 f (12 MiB)
  float* seg32   = kp + 3145728;            // 524,288 f (2 MiB)

  const int M = B_ * L_;                    // 32768

  // split all 3 weights in one launch (into d_out scratch)
  wsplit3_kernel<<<dim3(1024, 3), 256, 0, stream>>>(Wq, Wk, Wv, Bt3);

  // q+k projections (3-term split, f32 out) in ONE launch; v (bf16 out) separate
  gemm_proj<3, 0><<<dim3(M / 128, 4, 2), 256, 0, stream>>>(
      q_in, k_in, Bt3, Bt3 + 524288, qp, kp);
  gemm_proj<1, 1><<<dim3(M / 128, 4, 1), 256, 0, stream>>>(
      v_in, v_in, Bt3 + 1048576, Bt3 + 1048576, vbf, vbf);

  // exact f32 dot + two-level top-40
  dotsel_kernel<<<dim3(BH, 8), 256, 0, stream>>>(qp, kp, indx, cand);
  merge_topk<<<BH, 64, 0, stream>>>(cand, mtop);
  gather_q_kernel<<<(BH * 48 * 64) / 256, 256, 0, stream>>>(qp, mtop, qredbf);

  // attention: scores (stages K from f32 kp) -> softmax -> PV (bf16 V)
  scores_mfma<<<dim3(BH, 16), 256, 0, stream>>>(qredbf, kp, mtop, S);
  softmax_kernel<<<BH * U_, 256, 0, stream>>>(S);
  pv_mfma<<<dim3(BH, 8), 256, 0, stream>>>(S, vbf, partial);

  // cumsum of v -> ctx (overwrites qp region; S dead now)
  cumsumA<<<dim3(BH, 16), 256, 0, stream>>>(vbf, seg32);
  cumsumB<<<dim3(BH, 16), 256, 0, stream>>>(vbf, seg32, ctx);

  // merge partials + scatter
  scatter_kernel<<<(BH * U_ * 64) / 256, 256, 0, stream>>>(partial, mtop, ctx);

  // out = ctx @ Wo via MFMA (plain bf16) — fully overwrites d_out (incl. Bt3 scratch)
  wo_prep<<<128, 256, 0, stream>>>(Wo, WoT);
  gemm_out<<<M / 64, 256, 0, stream>>>(ctx, WoT, out);
}

// Round 10
// 337.809 us; speedup vs baseline: 1.2482x; 1.2482x over previous
//
#include <hip/hip_runtime.h>
#include <hip/hip_bf16.h>
#include <math.h>

#define B_   16
#define L_   2048
#define DIN  512
#define HID_ 512
#define H_   8
#define D_   64
#define U_   40
#define BH   (B_*H_)     // 128

typedef unsigned short u16;
typedef unsigned int u32;
typedef unsigned long long u64;
typedef __bf16 bf16x8 __attribute__((ext_vector_type(8)));
typedef float f32x4 __attribute__((ext_vector_type(4)));

__device__ __forceinline__ u16 f2bf(float x) {            // RNE via HW cvt
  __bf16 b = (__bf16)x;
  return __builtin_bit_cast(unsigned short, b);
}
__device__ __forceinline__ float bf2f(u16 h) {
  return __uint_as_float(((unsigned)h) << 16);
}
__device__ __forceinline__ float bflo(u32 x) { return __uint_as_float(x << 16); }
__device__ __forceinline__ float bfhi(u32 x) { return __uint_as_float(x & 0xFFFF0000u); }
__device__ __forceinline__ u32 pk2(float a, float b) {
  return (u32)f2bf(a) | ((u32)f2bf(b) << 16);
}
__device__ __forceinline__ void gload16(const u16* g, u16* l) {
  __builtin_amdgcn_global_load_lds(
      (__attribute__((address_space(1))) void*)(g),
      (__attribute__((address_space(3))) void*)(l), 16, 0, 0);
}
__device__ __forceinline__ u64 mkkey(float Mv, int l) {
  u32 fb = __float_as_uint(Mv);
  u32 mapped = (fb & 0x80000000u) ? ~fb : (fb | 0x80000000u);
  return ((u64)mapped << 32) | (u64)(0xFFFFFFFFu - (u32)l);
}

// ---------------- weight split+transpose (all 3): W f32 -> Bt3[y] bf16 [512][1024] ---
__global__ __launch_bounds__(256)
void wsplit3_kernel(const float* __restrict__ Wq, const float* __restrict__ Wk,
                    const float* __restrict__ Wv, u16* __restrict__ Bt3) {
  const float* W = (blockIdx.y == 0) ? Wq : (blockIdx.y == 1) ? Wk : Wv;
  u16* Bt = Bt3 + (size_t)blockIdx.y * 524288;
  int tid = blockIdx.x * 256 + threadIdx.x;
  int n = tid & 511, k = tid >> 9;
  float a = W[(size_t)k * 512 + n];
  u16 hi = f2bf(a);
  u16 lo = f2bf(a - bf2f(hi));
  int kb = k >> 5, kc = k & 31;
  int slotH = kc >> 3, wi = kc & 7;
  int swzH = (slotH     ^ (n & 7)) << 3;
  int swzL = ((4+slotH) ^ (n & 7)) << 3;
  Bt[(size_t)n * 1024 + kb * 64 + swzH + wi] = hi;
  Bt[(size_t)n * 1024 + kb * 64 + swzL + wi] = lo;
}

// ---------------- projection GEMM (round-8 proven structure + XCD swizzle) ----------
// 1-D grid of 1024; decode so the 4 col-tiles of one A-row-panel land on the same
// XCD slot (bids differ by 8) and dispatch close together -> A reuse in that L2.
// NPASS=3: 3-term bf16 split (q/k, f32 out). NPASS=1: plain bf16 (v), OUTBF u16 out.
template<int NPASS, int OUTBF>
__global__ __launch_bounds__(256, 4)
void gemm_proj(const float* __restrict__ A, const u16* __restrict__ Bt,
               void* __restrict__ C) {
  __shared__ u16 As[128 * 64];
  __shared__ u16 Bs[128 * 64];
  const int bid = blockIdx.x;
  const int g = bid >> 3;
  const int xb = (bid & 7) + ((g >> 2) << 3);   // row tile 0..255
  const int yb = g & 3;                         // col tile 0..3
  const int t = threadIdx.x;
  const int w = t >> 6, lane = t & 63;
  const int lhi = lane >> 4, l16 = lane & 15;
  const int row0 = xb * 128, col0 = yb * 128;
  const int wrow = (w >> 1) * 64, wcol = (w & 1) * 64;

  const u16* gB = Bt + (size_t)(col0 + w * 32 + (lane >> 3)) * 1024 + (lane & 7) * 8;
  u16* lB = &Bs[(w * 32) * 64];

  f32x4 acc[4][4];
  #pragma unroll
  for (int i = 0; i < 4; ++i)
    #pragma unroll
    for (int j = 0; j < 4; ++j) acc[i][j] = (f32x4){0.f, 0.f, 0.f, 0.f};

  for (int kb = 0; kb < 16; ++kb) {
    #pragma unroll
    for (int i = 0; i < 4; ++i)
      gload16(gB + kb * 64 + (size_t)i * 8 * 1024, lB + i * 8 * 64);
    #pragma unroll
    for (int i = 0; i < 4; ++i) {
      int r  = (t >> 3) + 32 * i;
      int c4 = (t & 7) * 4;
      float4 v = *reinterpret_cast<const float4*>(
          &A[(size_t)(row0 + r) * 512 + kb * 32 + c4]);
      ushort4 h4;
      h4.x = f2bf(v.x); h4.y = f2bf(v.y); h4.z = f2bf(v.z); h4.w = f2bf(v.w);
      int slotH = c4 >> 3, wi = c4 & 7;
      int baseH = r * 64 + (((slotH)     ^ (r & 7)) << 3) + wi;
      *reinterpret_cast<ushort4*>(&As[baseH]) = h4;
      if constexpr (NPASS == 3) {
        ushort4 lo4;
        lo4.x = f2bf(v.x - bf2f(h4.x)); lo4.y = f2bf(v.y - bf2f(h4.y));
        lo4.z = f2bf(v.z - bf2f(h4.z)); lo4.w = f2bf(v.w - bf2f(h4.w));
        int baseL = r * 64 + (((4 + slotH) ^ (r & 7)) << 3) + wi;
        *reinterpret_cast<ushort4*>(&As[baseL]) = lo4;
      }
    }
    __syncthreads();

    // B fragments once (hi + lo), then A rows once, all MFMAs per row
    bf16x8 bfH[4], bfL[4];
    #pragma unroll
    for (int j = 0; j < 4; ++j) {
      int cb = wcol + j * 16 + l16;
      bfH[j] = *reinterpret_cast<const bf16x8*>(
          &Bs[cb * 64 + ((lhi ^ (cb & 7)) << 3)]);
      if constexpr (NPASS == 3)
        bfL[j] = *reinterpret_cast<const bf16x8*>(
            &Bs[cb * 64 + (((4 + lhi) ^ (cb & 7)) << 3)]);
    }
    #pragma unroll
    for (int i = 0; i < 4; ++i) {
      int ra = wrow + i * 16 + l16;
      bf16x8 aH = *reinterpret_cast<const bf16x8*>(
          &As[ra * 64 + ((lhi ^ (ra & 7)) << 3)]);
      #pragma unroll
      for (int j = 0; j < 4; ++j)
        acc[i][j] = __builtin_amdgcn_mfma_f32_16x16x32_bf16(aH, bfH[j], acc[i][j], 0, 0, 0);
      if constexpr (NPASS == 3) {
        bf16x8 aL = *reinterpret_cast<const bf16x8*>(
            &As[ra * 64 + (((4 + lhi) ^ (ra & 7)) << 3)]);
        #pragma unroll
        for (int j = 0; j < 4; ++j)
          acc[i][j] = __builtin_amdgcn_mfma_f32_16x16x32_bf16(aH, bfL[j], acc[i][j], 0, 0, 0);
        #pragma unroll
        for (int j = 0; j < 4; ++j)
          acc[i][j] = __builtin_amdgcn_mfma_f32_16x16x32_bf16(aL, bfH[j], acc[i][j], 0, 0, 0);
      }
    }
    __syncthreads();
  }
  #pragma unroll
  for (int i = 0; i < 4; ++i)
    #pragma unroll
    for (int j = 0; j < 4; ++j)
      #pragma unroll
      for (int r = 0; r < 4; ++r) {
        size_t idx = (size_t)(row0 + wrow + i * 16 + lhi * 4 + r) * 512
                     + col0 + wcol + j * 16 + l16;
        if constexpr (OUTBF) ((u16*)C)[idx] = f2bf(acc[i][j][r]);
        else                 ((float*)C)[idx] = acc[i][j][r];
      }
}

// ---------------- dot + per-chunk top-40 candidates (exact f32) ---------------------
__global__ __launch_bounds__(256)
void dotsel_kernel(const float* __restrict__ qp, const float* __restrict__ kp,
                   const int* __restrict__ indx, u64* __restrict__ cand) {
  __shared__ u64 keys[256];
  __shared__ u64 wmax[2][4];
  const int bh = blockIdx.x, ch = blockIdx.y;
  const int t = threadIdx.x, w = t >> 6, lane = t & 63;
  const size_t boff = (size_t)bh * 131072;
  const int l0 = ch * 256 + w * 64;
  const float cUL = 40.0f / 2048.0f;
  const int li = lane >> 4;
  const int dq = lane & 15;

  #pragma unroll 4
  for (int i = 0; i < 16; ++i) {
    int l = l0 + i * 4 + li;
    int ls = indx[l];
    float4 q4 = *reinterpret_cast<const float4*>(&qp[boff + (size_t)l * 64 + dq * 4]);
    float4 k4 = *reinterpret_cast<const float4*>(&kp[boff + (size_t)ls * 64 + dq * 4]);
    float p = q4.x * k4.x + q4.y * k4.y + q4.z * k4.z + q4.w * k4.w;
    p += __shfl_xor(p, 1, 64);
    p += __shfl_xor(p, 2, 64);
    p += __shfl_xor(p, 4, 64);
    p += __shfl_xor(p, 8, 64);
    if (dq == 0) {
      float Mv = p - p * cUL;
      keys[w * 64 + i * 4 + li] = mkkey(Mv, l);
    }
  }
  __syncthreads();

  u64 myk = keys[t];
  for (int u = 0; u < U_; ++u) {
    u64 b = myk;
    #pragma unroll
    for (int off = 32; off >= 1; off >>= 1) {
      u64 v = __shfl_xor(b, off, 64);
      if (v > b) b = v;
    }
    if (lane == 0) wmax[u & 1][w] = b;
    __syncthreads();
    const u64* wm = wmax[u & 1];
    u64 m = wm[0];
    if (wm[1] > m) m = wm[1];
    if (wm[2] > m) m = wm[2];
    if (wm[3] > m) m = wm[3];
    if (myk == m) myk = 0;              // unique keys: owner clears
    if (t == 0) cand[((size_t)(bh * 8 + ch)) * U_ + u] = m;
  }
}

// ---------------- merge 8x40 candidates -> global top-40 (1 wave per bh) ------------
__global__ __launch_bounds__(64)
void merge_topk(const u64* __restrict__ cand, int* __restrict__ mtop) {
  const int bh = blockIdx.x;
  const int lane = threadIdx.x;
  u64 c0 = cand[(size_t)bh * 320 + 0 * 64 + lane];
  u64 c1 = cand[(size_t)bh * 320 + 1 * 64 + lane];
  u64 c2 = cand[(size_t)bh * 320 + 2 * 64 + lane];
  u64 c3 = cand[(size_t)bh * 320 + 3 * 64 + lane];
  u64 c4 = cand[(size_t)bh * 320 + 4 * 64 + lane];
  for (int u = 0; u < U_; ++u) {
    u64 b = c0;
    if (c1 > b) b = c1;
    if (c2 > b) b = c2;
    if (c3 > b) b = c3;
    if (c4 > b) b = c4;
    #pragma unroll
    for (int off = 32; off >= 1; off >>= 1) {
      u64 v = __shfl_xor(b, off, 64);
      if (v > b) b = v;
    }
    if (c0 == b) c0 = 0;
    if (c1 == b) c1 = 0;
    if (c2 == b) c2 = 0;
    if (c3 == b) c3 = 0;
    if (c4 == b) c4 = 0;
    if (lane == 0) mtop[bh * U_ + u] = (int)(0xFFFFFFFFu - (u32)b);
  }
}

// ---------------- gather selected q rows -> bf16, x0.125, 48-row padded -------------
__global__ __launch_bounds__(256)
void gather_q_kernel(const float* __restrict__ qp, const int* __restrict__ mtop,
                     u16* __restrict__ qredbf) {
  int tid = blockIdx.x * 256 + threadIdx.x;   // BH*48*64 total
  int s = tid >> 6;
  int d = tid & 63;
  int bh = s / 48;
  int u = s - bh * 48;
  float val = 0.f;
  if (u < U_) {
    int m = mtop[bh * U_ + u];
    val = qp[(size_t)bh * (L_ * D_) + (size_t)m * D_ + d] * 0.125f;
  }
  qredbf[tid] = f2bf(val);
}

// ---------------- scores via MFMA: stages K from f32 kp; S bf16, mask fused ---------
__global__ __launch_bounds__(256)
void scores_mfma(const u16* __restrict__ qredbf, const float* __restrict__ kp,
                 const int* __restrict__ mtop, u16* __restrict__ S) {
  __shared__ u16 As[48 * 64];
  __shared__ u16 Bs[128 * 64];
  __shared__ int ms[U_];
  const int bh = blockIdx.x;
  const int l0 = blockIdx.y * 128;
  const int t = threadIdx.x, w = t >> 6, lane = t & 63;
  const int lhi = lane >> 4, l16 = lane & 15;

  for (int e = t; e < 384; e += 256) {
    int r = e >> 3, s = e & 7;
    *reinterpret_cast<uint4*>(&As[r * 64 + ((s ^ (r & 7)) << 3)]) =
        *reinterpret_cast<const uint4*>(&qredbf[(size_t)bh * 3072 + e * 8]);
  }
  #pragma unroll
  for (int ee = 0; ee < 4; ++ee) {
    int e = t + ee * 256;
    int r = e >> 3, s = e & 7;
    const float* src = &kp[(size_t)bh * 131072 + (size_t)(l0 + r) * 64 + s * 8];
    float4 va = *reinterpret_cast<const float4*>(src);
    float4 vb = *reinterpret_cast<const float4*>(src + 4);
    uint4 w4 = make_uint4(pk2(va.x, va.y), pk2(va.z, va.w),
                          pk2(vb.x, vb.y), pk2(vb.z, vb.w));
    *reinterpret_cast<uint4*>(&Bs[r * 64 + ((s ^ (r & 7)) << 3)]) = w4;
  }
  if (t < U_) ms[t] = mtop[bh * U_ + t];
  __syncthreads();

  f32x4 acc[3][2];
  #pragma unroll
  for (int m = 0; m < 3; ++m)
    #pragma unroll
    for (int n = 0; n < 2; ++n) acc[m][n] = (f32x4){0.f, 0.f, 0.f, 0.f};

  #pragma unroll
  for (int ks = 0; ks < 2; ++ks) {
    bf16x8 a[3], b[2];
    #pragma unroll
    for (int m = 0; m < 3; ++m) {
      int r = m * 16 + l16;
      a[m] = *reinterpret_cast<const bf16x8*>(
          &As[r * 64 + (((ks * 4 + lhi) ^ (r & 7)) << 3)]);
    }
    #pragma unroll
    for (int n = 0; n < 2; ++n) {
      int cb = w * 32 + n * 16 + l16;
      b[n] = *reinterpret_cast<const bf16x8*>(
          &Bs[cb * 64 + (((ks * 4 + lhi) ^ (cb & 7)) << 3)]);
    }
    #pragma unroll
    for (int m = 0; m < 3; ++m)
      #pragma unroll
      for (int n = 0; n < 2; ++n)
        acc[m][n] = __builtin_amdgcn_mfma_f32_16x16x32_bf16(a[m], b[n], acc[m][n], 0, 0, 0);
  }

  #pragma unroll
  for (int m = 0; m < 3; ++m)
    #pragma unroll
    for (int n = 0; n < 2; ++n)
      #pragma unroll
      for (int r = 0; r < 4; ++r) {
        int u = m * 16 + lhi * 4 + r;
        if (u < U_) {
          int l = l0 + w * 32 + n * 16 + l16;
          float val = acc[m][n][r];
          if (l > ms[u]) val = -INFINITY;
          S[((size_t)bh * 48 + u) * 2048 + l] = f2bf(val);
        }
      }
}

// ---------------- row softmax over l, bf16 in-place (S -> P) ------------------------
__global__ __launch_bounds__(256)
void softmax_kernel(u16* __restrict__ S) {
  __shared__ float red[4];
  const int rr = blockIdx.x;            // bh*40 + u
  const int bh = rr / U_;
  const int u = rr - bh * U_;
  const int t = threadIdx.x;
  uint4* rp = reinterpret_cast<uint4*>(&S[((size_t)bh * 48 + u) * 2048]);
  uint4 raw = rp[t];
  float f[8];
  f[0] = bflo(raw.x); f[1] = bfhi(raw.x); f[2] = bflo(raw.y); f[3] = bfhi(raw.y);
  f[4] = bflo(raw.z); f[5] = bfhi(raw.z); f[6] = bflo(raw.w); f[7] = bfhi(raw.w);
  float m = f[0];
  #pragma unroll
  for (int i = 1; i < 8; ++i) m = fmaxf(m, f[i]);
  #pragma unroll
  for (int off = 32; off >= 1; off >>= 1) m = fmaxf(m, __shfl_xor(m, off, 64));
  if ((t & 63) == 0) red[t >> 6] = m;
  __syncthreads();
  m = fmaxf(fmaxf(red[0], red[1]), fmaxf(red[2], red[3]));
  __syncthreads();
  float s = 0.f;
  #pragma unroll
  for (int i = 0; i < 8; ++i) { f[i] = expf(f[i] - m); s += f[i]; }
  #pragma unroll
  for (int off = 32; off >= 1; off >>= 1) s += __shfl_xor(s, off, 64);
  if ((t & 63) == 0) red[t >> 6] = s;
  __syncthreads();
  s = red[0] + red[1] + red[2] + red[3];
  float inv = 1.0f / s;
  uint4 o;
  o.x = pk2(f[0] * inv, f[1] * inv);
  o.y = pk2(f[2] * inv, f[3] * inv);
  o.z = pk2(f[4] * inv, f[5] * inv);
  o.w = pk2(f[6] * inv, f[7] * inv);
  rp[t] = o;
}

// ---------------- PV via MFMA, split-K=8, V (bf16) transposed in-kernel -------------
__global__ __launch_bounds__(256)
void pv_mfma(const u16* __restrict__ Pbf, const u16* __restrict__ vbf,
             float* __restrict__ partial) {
  __shared__ u16 Ps[48 * 128];
  __shared__ u16 Vs[64 * 128];
  const int bh = blockIdx.x, kh = blockIdx.y;
  const int t = threadIdx.x, w = t >> 6, lane = t & 63;
  const int lhi = lane >> 4, l16 = lane & 15;
  const size_t vbase = (size_t)bh * 131072;
  f32x4 acc[3];
  #pragma unroll
  for (int m = 0; m < 3; ++m) acc[m] = (f32x4){0.f, 0.f, 0.f, 0.f};

  for (int ch = 0; ch < 2; ++ch) {
    const int lb = kh * 256 + ch * 128;
    for (int e = t; e < 768; e += 256) {
      int r = e >> 4, s = e & 15;
      int sw = (s & 8) | ((s & 7) ^ (r & 7));
      *reinterpret_cast<uint4*>(&Ps[r * 128 + (sw << 3)]) =
          *reinterpret_cast<const uint4*>(&Pbf[((size_t)bh * 48 + r) * 2048 + lb + s * 8]);
    }
    #pragma unroll
    for (int j = 0; j < 16; ++j) {
      int ll = w * 32 + 2 * j;
      u16 ua = vbf[vbase + (size_t)(lb + ll) * 64 + lane];
      u16 ub = vbf[vbase + (size_t)(lb + ll + 1) * 64 + lane];
      u32 pk = (u32)ua | ((u32)ub << 16);
      int s = ll >> 3;
      int sw = (s & 8) | ((s & 7) ^ (lane & 7));
      *reinterpret_cast<u32*>(&Vs[lane * 128 + (sw << 3) + (ll & 7)]) = pk;
    }
    __syncthreads();
    #pragma unroll
    for (int ks = 0; ks < 4; ++ks) {
      bf16x8 b;
      { int cb = w * 16 + l16; int s = ks * 4 + lhi;
        int sw = (s & 8) | ((s & 7) ^ (cb & 7));
        b = *reinterpret_cast<const bf16x8*>(&Vs[cb * 128 + (sw << 3)]); }
      #pragma unroll
      for (int m = 0; m < 3; ++m) {
        int r = m * 16 + l16; int s = ks * 4 + lhi;
        int sw = (s & 8) | ((s & 7) ^ (r & 7));
        bf16x8 a = *reinterpret_cast<const bf16x8*>(&Ps[r * 128 + (sw << 3)]);
        acc[m] = __builtin_amdgcn_mfma_f32_16x16x32_bf16(a, b, acc[m], 0, 0, 0);
      }
    }
    __syncthreads();
  }
  #pragma unroll
  for (int m = 0; m < 3; ++m)
    #pragma unroll
    for (int r = 0; r < 4; ++r) {
      int u = m * 16 + lhi * 4 + r;
      partial[(((size_t)kh * 128 + bh) * 48 + u) * 64 + w * 16 + l16] = acc[m][r];
    }
}

// ---------------- cumsum 2-phase over bf16 v -> f32 ctx -----------------------------
__global__ __launch_bounds__(256)
void cumsumA(const u16* __restrict__ vbf, float* __restrict__ seg32) {
  int bh = blockIdx.x, sg = blockIdx.y;
  int t = threadIdx.x, w = t >> 6, lane = t & 63;
  int g = sg * 4 + w;
  size_t base = (size_t)bh * 131072 + (size_t)g * 32 * 64;
  float s = 0.f;
  for (int i = 0; i < 32; ++i) s += bf2f(vbf[base + i * 64 + lane]);
  seg32[((size_t)bh * 64 + g) * 64 + lane] = s;
}
__global__ __launch_bounds__(256)
void cumsumB(const u16* __restrict__ vbf, const float* __restrict__ seg32,
             float* __restrict__ ctx) {
  int bh = blockIdx.x, sg = blockIdx.y;
  int t = threadIdx.x, w = t >> 6, lane = t & 63;
  int g = sg * 4 + w;
  float run = 0.f;
  for (int s = 0; s < g; ++s) run += seg32[((size_t)bh * 64 + s) * 64 + lane];
  size_t base = (size_t)bh * 131072 + (size_t)g * 32 * 64;
  for (int i = 0; i < 32; ++i) {
    run += bf2f(vbf[base + i * 64 + lane]);
    ctx[base + i * 64 + lane] = run;
  }
}

// ---------------- merge 8 partials + scatter into ctx -------------------------------
__global__ __launch_bounds__(256)
void scatter_kernel(const float* __restrict__ partial, const int* __restrict__ mtop,
                    float* __restrict__ ctx) {
  int tid = blockIdx.x * 256 + threadIdx.x;
  int s = tid >> 6;
  if (s >= BH * U_) return;
  int d = tid & 63;
  int bh = s / U_;
  int u = s - bh * U_;
  float a = 0.f;
  #pragma unroll
  for (int c = 0; c < 8; ++c)
    a += partial[(((size_t)(c * 128 + bh)) * 48 + u) * 64 + d];
  ctx[(size_t)bh * 131072 + (size_t)mtop[s] * 64 + d] = a;
}

// ---------------- Wo -> bf16, transposed + swizzled: WoT[j][512] --------------------
__global__ __launch_bounds__(256)
void wo_prep(const float* __restrict__ Wo, u16* __restrict__ WoT) {
  int tid = blockIdx.x * 256 + threadIdx.x;   // 32768
  int j = tid >> 9, k = tid & 511;
  float v = Wo[(size_t)k * 64 + j];
  int k0 = k & ~63, ko = k & 63;
  int ks = ko >> 5, kc = ko & 31;
  int slot = (ks * 4 + (kc >> 3)) ^ (j & 7);
  WoT[(size_t)j * 512 + k0 + (slot << 3) + (kc & 7)] = f2bf(v);
}

// ---------------- out GEMM via MFMA (plain bf16): out[M][64] = ctx @ Wo -------------
__global__ __launch_bounds__(256, 6)
void gemm_out(const float* __restrict__ ctx, const u16* __restrict__ WoT,
              float* __restrict__ out) {
  __shared__ u16 As[64 * 64];
  __shared__ u16 Bs[64 * 64];
  const int t = threadIdx.x, w = t >> 6, lane = t & 63;
  const int lhi = lane >> 4, l16 = lane & 15;
  const int row0 = blockIdx.x * 64;
  f32x4 acc[4];
  #pragma unroll
  for (int j = 0; j < 4; ++j) acc[j] = (f32x4){0.f, 0.f, 0.f, 0.f};

  for (int k0 = 0; k0 < 512; k0 += 64) {
    #pragma unroll
    for (int ii = 0; ii < 2; ++ii) {
      int e = t + ii * 256;
      int j = e >> 3, s = e & 7;
      gload16(WoT + (size_t)j * 512 + k0 + s * 8, Bs + (size_t)(w * 64 + ii * 256) * 8);
    }
    #pragma unroll
    for (int ii = 0; ii < 2; ++ii) {
      int e = t + ii * 256;
      int r = e >> 3, s = e & 7;
      const float* src = &ctx[(size_t)(row0 + r) * 512 + k0 + s * 8];
      float4 va = *reinterpret_cast<const float4*>(src);
      float4 vb = *reinterpret_cast<const float4*>(src + 4);
      uint4 w4 = make_uint4(pk2(va.x, va.y), pk2(va.z, va.w),
                            pk2(vb.x, vb.y), pk2(vb.z, vb.w));
      *reinterpret_cast<uint4*>(&As[r * 64 + ((s ^ (r & 7)) << 3)]) = w4;
    }
    __syncthreads();
    #pragma unroll
    for (int ks = 0; ks < 2; ++ks) {
      int r = w * 16 + l16;
      bf16x8 a = *reinterpret_cast<const bf16x8*>(
          &As[r * 64 + (((ks * 4 + lhi) ^ (r & 7)) << 3)]);
      #pragma unroll
      for (int jf = 0; jf < 4; ++jf) {
        int cb = jf * 16 + l16;
        bf16x8 b = *reinterpret_cast<const bf16x8*>(
            &Bs[cb * 64 + (((ks * 4 + lhi) ^ (cb & 7)) << 3)]);
        acc[jf] = __builtin_amdgcn_mfma_f32_16x16x32_bf16(a, b, acc[jf], 0, 0, 0);
      }
    }
    __syncthreads();
  }
  #pragma unroll
  for (int jf = 0; jf < 4; ++jf)
    #pragma unroll
    for (int r = 0; r < 4; ++r)
      out[(size_t)(row0 + w * 16 + lhi * 4 + r) * 64 + jf * 16 + l16] = acc[jf][r];
}

extern "C" void kernel_launch(void* const* d_in, const int* in_sizes, int n_in,
                              void* d_out, int out_size, void* d_ws, size_t ws_size,
                              hipStream_t stream) {
  const float* q_in = (const float*)d_in[0];
  const float* k_in = (const float*)d_in[1];
  const float* v_in = (const float*)d_in[2];
  const float* Wq   = (const float*)d_in[3];
  const float* Wk   = (const float*)d_in[4];
  const float* Wv   = (const float*)d_in[5];
  const float* Wo   = (const float*)d_in[6];
  const int*   indx = (const int*)d_in[7];
  float* out = (float*)d_out;

  float* ws = (float*)d_ws;
  float* qp   = ws;                         // 16,777,216 f (64 MiB)
  float* kp   = ws + 16777216;
  u16*   vbf  = (u16*)(ws + 33554432);      // 16M u16 (32 MiB) — v projection in bf16
  u64*   cand = (u64*)(ws + 50331648);      // 320 KiB
  u16*   WoT  = (u16*)cand;                 // 64 KiB — after cand dead
  u16*   qredbf = (u16*)(ws + 50593792);    // 393,216 u16
  int*   mtop = (int*)(ws + 50921472);      // 5,120 ints
  // d_out used as scratch for split weights (3 MiB of 8 MiB); gemm_out fully
  // overwrites d_out at the end, so this is replay-safe.
  u16*   Bt3  = (u16*)d_out;
  // qp region reuse (qp f32 dead after gather_q):
  u16*   S    = (u16*)qp;                   // 12.6M u16 (24 MiB)
  float* ctx  = qp;                         // cumsum output (after S dead)
  // kp region reuse (kp f32 dead after scores_mfma):
  float* partial = kp;                      // 3,145,728 f (12 MiB)
  float* seg32   = kp + 3145728;            // 524,288 f (2 MiB)

  const int M = B_ * L_;                    // 32768

  // split all 3 weights in one launch (into d_out scratch)
  wsplit3_kernel<<<dim3(1024, 3), 256, 0, stream>>>(Wq, Wk, Wv, Bt3);

  // projections: q/k exact 3-term split (f32 out), v plain bf16 (u16 out)
  gemm_proj<3, 0><<<1024, 256, 0, stream>>>(q_in, Bt3, qp);
  gemm_proj<3, 0><<<1024, 256, 0, stream>>>(k_in, Bt3 + 524288, kp);
  gemm_proj<1, 1><<<1024, 256, 0, stream>>>(v_in, Bt3 + 1048576, vbf);

  // exact f32 dot + two-level top-40
  dotsel_kernel<<<dim3(BH, 8), 256, 0, stream>>>(qp, kp, indx, cand);
  merge_topk<<<BH, 64, 0, stream>>>(cand, mtop);
  gather_q_kernel<<<(BH * 48 * 64) / 256, 256, 0, stream>>>(qp, mtop, qredbf);

  // attention: scores (stages K from f32 kp) -> softmax -> PV (bf16 V)
  scores_mfma<<<dim3(BH, 16), 256, 0, stream>>>(qredbf, kp, mtop, S);
  softmax_kernel<<<BH * U_, 256, 0, stream>>>(S);
  pv_mfma<<<dim3(BH, 8), 256, 0, stream>>>(S, vbf, partial);

  // cumsum of v -> ctx (overwrites qp region; S dead now)
  cumsumA<<<dim3(BH, 16), 256, 0, stream>>>(vbf, seg32);
  cumsumB<<<dim3(BH, 16), 256, 0, stream>>>(vbf, seg32, ctx);

  // merge partials + scatter
  scatter_kernel<<<(BH * U_ * 64) / 256, 256, 0, stream>>>(partial, mtop, ctx);

  // out = ctx @ Wo via MFMA (plain bf16) — fully overwrites d_out (incl. Bt3 scratch)
  wo_prep<<<128, 256, 0, stream>>>(Wo, WoT);
  gemm_out<<<M / 64, 256, 0, stream>>>(ctx, WoT, out);
}